// Round 1
// baseline (1612.570 us; speedup 1.0000x reference)
//
#include <hip/hip_runtime.h>

constexpr int NB  = 32;
constexpr int NS  = 1024;
constexpr int ND  = 256;
constexpr int NH  = 8;
constexpr int NDH = 32;
constexpr int NF  = 512;
constexpr int NM  = NB * NS;          // 32768 rows
#define RSD 0.17677669529663687f       // 1/sqrt(32)

// ---------------------------------------------------------------------------
// QKV projection: y = x @ W.T + b, scattered to [B,H,S,d]; z=0 adds hidden and
// applies the 1/sqrt(d) scale (folded into q).
// ---------------------------------------------------------------------------
__global__ __launch_bounds__(256) void gemm_qkv(
    const float* __restrict__ x,
    const float* __restrict__ Wq, const float* __restrict__ Wk, const float* __restrict__ Wv,
    const float* __restrict__ bq, const float* __restrict__ bk, const float* __restrict__ bv,
    const float* __restrict__ hidden,
    float* __restrict__ qp, float* __restrict__ kb, float* __restrict__ vb)
{
    __shared__ float As[16][68];
    __shared__ float Bs[16][68];
    const int t = threadIdx.x;
    const int z = blockIdx.z;
    const int rbase = blockIdx.y << 6;
    const int jbase = blockIdx.x << 6;
    const float* W    = (z == 0) ? Wq : (z == 1) ? Wk : Wv;
    const float* bias = (z == 0) ? bq : (z == 1) ? bk : bv;
    float* outp       = (z == 0) ? qp : (z == 1) ? kb : vb;

    const int lr = t >> 2;
    const int lc = (t & 3) << 2;
    const int tx = t & 15, ty = t >> 4;
    float acc[4][4] = {};

    for (int k0 = 0; k0 < ND; k0 += 16) {
        float4 av = *(const float4*)&x[(size_t)(rbase + lr) * ND + k0 + lc];
        float4 wv = *(const float4*)&W[(size_t)(jbase + lr) * ND + k0 + lc];
        __syncthreads();
        As[lc + 0][lr] = av.x; As[lc + 1][lr] = av.y; As[lc + 2][lr] = av.z; As[lc + 3][lr] = av.w;
        Bs[lc + 0][lr] = wv.x; Bs[lc + 1][lr] = wv.y; Bs[lc + 2][lr] = wv.z; Bs[lc + 3][lr] = wv.w;
        __syncthreads();
        #pragma unroll
        for (int kk = 0; kk < 16; ++kk) {
            float4 a4 = *(const float4*)&As[kk][ty << 2];
            float4 b4 = *(const float4*)&Bs[kk][tx << 2];
            float a[4] = {a4.x, a4.y, a4.z, a4.w};
            float b[4] = {b4.x, b4.y, b4.z, b4.w};
            #pragma unroll
            for (int i2 = 0; i2 < 4; ++i2)
                #pragma unroll
                for (int j2 = 0; j2 < 4; ++j2)
                    acc[i2][j2] += a[i2] * b[j2];
        }
    }

    const int jcol = jbase + (tx << 2);
    const int hh = jcol >> 5, dd0 = jcol & 31;
    float4 bias4 = *(const float4*)&bias[jcol];
    #pragma unroll
    for (int i2 = 0; i2 < 4; ++i2) {
        int r = rbase + (ty << 2) + i2;
        int b_i = r >> 10, s_i = r & 1023;
        size_t idx = (((size_t)(b_i * NH + hh)) * NS + s_i) * NDH + dd0;
        float4 o;
        o.x = acc[i2][0] + bias4.x;
        o.y = acc[i2][1] + bias4.y;
        o.z = acc[i2][2] + bias4.z;
        o.w = acc[i2][3] + bias4.w;
        if (z == 0) {
            float4 hv = *(const float4*)&hidden[idx];
            o.x = (o.x + hv.x) * RSD;
            o.y = (o.y + hv.y) * RSD;
            o.z = (o.z + hv.z) * RSD;
            o.w = (o.w + hv.w) * RSD;
        }
        *(float4*)&outp[idx] = o;
    }
}

// ---------------------------------------------------------------------------
// Generic row-major GEMM  out = epi(A @ W.T + bias)
// epi: 0 -> 2*(v+b)  (O-proj + doubling)
//      1 -> relu(v+b) (FFN1)
//      2 -> out += v+b (FFN2 accumulate into h)
// ---------------------------------------------------------------------------
__global__ __launch_bounds__(256) void gemm_epi(
    const float* __restrict__ A, const float* __restrict__ W,
    const float* __restrict__ bias, float* __restrict__ out,
    int N, int K, int epi)
{
    __shared__ float As[16][68];
    __shared__ float Bs[16][68];
    const int t = threadIdx.x;
    const int rbase = blockIdx.y << 6;
    const int jbase = blockIdx.x << 6;
    const int lr = t >> 2;
    const int lc = (t & 3) << 2;
    const int tx = t & 15, ty = t >> 4;
    float acc[4][4] = {};

    for (int k0 = 0; k0 < K; k0 += 16) {
        float4 av = *(const float4*)&A[(size_t)(rbase + lr) * K + k0 + lc];
        float4 wv = *(const float4*)&W[(size_t)(jbase + lr) * K + k0 + lc];
        __syncthreads();
        As[lc + 0][lr] = av.x; As[lc + 1][lr] = av.y; As[lc + 2][lr] = av.z; As[lc + 3][lr] = av.w;
        Bs[lc + 0][lr] = wv.x; Bs[lc + 1][lr] = wv.y; Bs[lc + 2][lr] = wv.z; Bs[lc + 3][lr] = wv.w;
        __syncthreads();
        #pragma unroll
        for (int kk = 0; kk < 16; ++kk) {
            float4 a4 = *(const float4*)&As[kk][ty << 2];
            float4 b4 = *(const float4*)&Bs[kk][tx << 2];
            float a[4] = {a4.x, a4.y, a4.z, a4.w};
            float b[4] = {b4.x, b4.y, b4.z, b4.w};
            #pragma unroll
            for (int i2 = 0; i2 < 4; ++i2)
                #pragma unroll
                for (int j2 = 0; j2 < 4; ++j2)
                    acc[i2][j2] += a[i2] * b[j2];
        }
    }

    const int jcol = jbase + (tx << 2);
    float4 bias4 = *(const float4*)&bias[jcol];
    #pragma unroll
    for (int i2 = 0; i2 < 4; ++i2) {
        int r = rbase + (ty << 2) + i2;
        float4 o;
        o.x = acc[i2][0] + bias4.x;
        o.y = acc[i2][1] + bias4.y;
        o.z = acc[i2][2] + bias4.z;
        o.w = acc[i2][3] + bias4.w;
        size_t oidx = (size_t)r * N + jcol;
        if (epi == 0) {
            o.x *= 2.f; o.y *= 2.f; o.z *= 2.f; o.w *= 2.f;
        } else if (epi == 1) {
            o.x = fmaxf(o.x, 0.f); o.y = fmaxf(o.y, 0.f);
            o.z = fmaxf(o.z, 0.f); o.w = fmaxf(o.w, 0.f);
        } else {
            float4 old = *(const float4*)&out[oidx];
            o.x += old.x; o.y += old.y; o.z += old.z; o.w += old.w;
        }
        *(float4*)&out[oidx] = o;
    }
}

// ---------------------------------------------------------------------------
// Fused scores + softmax. Block = 1024 threads = 64 q-rows of one (b,h).
// K [1024x32] staged in LDS (stride 36 floats, quad XOR-swizzled by (k>>2)&7).
// Thread (qr=t>>4, c=t&15) owns k = 64j + 4c + i  (j<16, i<4): 64 scores.
// ---------------------------------------------------------------------------
__global__ __launch_bounds__(1024) void attn_scores(
    const float* __restrict__ qp, const float* __restrict__ kb,
    float* __restrict__ attn)
{
    __shared__ float Kl[1024 * 36];   // 144 KB
    const int t = threadIdx.x;
    const int bh = blockIdx.y;
    const int q0 = blockIdx.x << 6;
    const float* kbase = kb + (size_t)bh * (NS * NDH);

    #pragma unroll
    for (int it = 0; it < 8; ++it) {
        int f = (it << 12) + (t << 2);
        int k = f >> 5;
        int dq = (f & 31) >> 2;
        int sw = dq ^ ((k >> 2) & 7);
        float4 g = *(const float4*)&kbase[f];
        *(float4*)&Kl[k * 36 + (sw << 2)] = g;
    }
    __syncthreads();

    const int qr = t >> 4, c = t & 15;
    const float* qrow = qp + ((size_t)bh * NS + q0 + qr) * NDH;
    float4 qv[8];
    #pragma unroll
    for (int dq = 0; dq < 8; ++dq) qv[dq] = *(const float4*)&qrow[dq << 2];

    const int xm = c & 7;
    float sc[64];
    float mx = -1e30f;
    #pragma unroll
    for (int j = 0; j < 16; ++j) {
        #pragma unroll
        for (int i = 0; i < 4; ++i) {
            int k = (j << 6) + (c << 2) + i;
            const float* kr = &Kl[k * 36];
            float s = 0.f;
            #pragma unroll
            for (int dq = 0; dq < 8; ++dq) {
                float4 kv = *(const float4*)&kr[(dq ^ xm) << 2];
                s += qv[dq].x * kv.x + qv[dq].y * kv.y + qv[dq].z * kv.z + qv[dq].w * kv.w;
            }
            sc[(j << 2) + i] = s;
            mx = fmaxf(mx, s);
        }
    }
    #pragma unroll
    for (int m = 8; m >= 1; m >>= 1) mx = fmaxf(mx, __shfl_xor(mx, m, 64));
    float sum = 0.f;
    #pragma unroll
    for (int u = 0; u < 64; ++u) { float e = __expf(sc[u] - mx); sc[u] = e; sum += e; }
    #pragma unroll
    for (int m = 8; m >= 1; m >>= 1) sum += __shfl_xor(sum, m, 64);
    const float inv = 1.f / sum;

    float* arow = attn + ((size_t)bh * NS + q0 + qr) * NS;
    #pragma unroll
    for (int j = 0; j < 16; ++j) {
        float4 o;
        o.x = sc[(j << 2) + 0] * inv;
        o.y = sc[(j << 2) + 1] * inv;
        o.z = sc[(j << 2) + 2] * inv;
        o.w = sc[(j << 2) + 3] * inv;
        *(float4*)&arow[(j << 6) + (c << 2)] = o;
    }
}

// ---------------------------------------------------------------------------
// PV: ctx[b,s, h*32+dd] = sum_k attn[b,h,q,k] * V[b,h,k,dd]. 64x32 tile, BK=128.
// ---------------------------------------------------------------------------
__global__ __launch_bounds__(256) void attn_pv(
    const float* __restrict__ attn, const float* __restrict__ vb,
    float* __restrict__ ctx)
{
    __shared__ float Asl[64 * 132];   // 33 KB
    __shared__ float Vs[128 * 36];    // 18 KB
    const int t = threadIdx.x;
    const int bh = blockIdx.y;
    const int q0 = blockIdx.x << 6;
    const float* arow  = attn + ((size_t)bh * NS + q0) * NS;
    const float* vbase = vb + (size_t)bh * (NS * NDH);

    const int dd4 = t & 7;
    const int rg  = t >> 3;          // 0..31
    const int r0  = rg << 1;
    float4 acc0 = {0.f, 0.f, 0.f, 0.f};
    float4 acc1 = {0.f, 0.f, 0.f, 0.f};

    for (int k0 = 0; k0 < NS; k0 += 128) {
        __syncthreads();
        #pragma unroll
        for (int it = 0; it < 8; ++it) {
            int f = (it << 10) + (t << 2);
            int r = f >> 7, kk = f & 127;
            *(float4*)&Asl[r * 132 + kk] = *(const float4*)&arow[((size_t)r << 10) + k0 + kk];
        }
        #pragma unroll
        for (int it = 0; it < 4; ++it) {
            int f = (it << 10) + (t << 2);
            int kk = f >> 5, dd = f & 31;
            *(float4*)&Vs[kk * 36 + dd] = *(const float4*)&vbase[(size_t)(k0 + kk) * NDH + dd];
        }
        __syncthreads();
        #pragma unroll 8
        for (int kk = 0; kk < 128; ++kk) {
            float4 v4 = *(const float4*)&Vs[kk * 36 + (dd4 << 2)];
            float a0 = Asl[r0 * 132 + kk];
            float a1 = Asl[(r0 + 1) * 132 + kk];
            acc0.x += a0 * v4.x; acc0.y += a0 * v4.y; acc0.z += a0 * v4.z; acc0.w += a0 * v4.w;
            acc1.x += a1 * v4.x; acc1.y += a1 * v4.y; acc1.z += a1 * v4.z; acc1.w += a1 * v4.w;
        }
    }

    const int b_i = bh >> 3, hh = bh & 7;
    size_t base = ((size_t)b_i * NS + q0 + r0) * ND + hh * NDH + (dd4 << 2);
    *(float4*)&ctx[base]      = acc0;
    *(float4*)&ctx[base + ND] = acc1;
}

// ---------------------------------------------------------------------------
// LayerNorm, one wave per row. mode 0: out = LN(x); mode 1: out = x + LN(x).
// ---------------------------------------------------------------------------
__global__ __launch_bounds__(256) void ln_kernel(
    const float* __restrict__ x, const float* __restrict__ g,
    const float* __restrict__ be, float* __restrict__ out, int mode)
{
    const int t = threadIdx.x;
    const int wave = t >> 6, lane = t & 63;
    const int row = (blockIdx.x << 2) + wave;
    const float* xr = x + (size_t)row * ND;
    float4 v = *(const float4*)&xr[lane << 2];
    float s = v.x + v.y + v.z + v.w;
    #pragma unroll
    for (int m = 32; m >= 1; m >>= 1) s += __shfl_xor(s, m, 64);
    float mu = s * (1.f / 256.f);
    float dx = v.x - mu, dy = v.y - mu, dz = v.z - mu, dw = v.w - mu;
    float s2 = dx * dx + dy * dy + dz * dz + dw * dw;
    #pragma unroll
    for (int m = 32; m >= 1; m >>= 1) s2 += __shfl_xor(s2, m, 64);
    float rs = rsqrtf(s2 * (1.f / 256.f) + 1e-5f);
    float4 gv = *(const float4*)&g[lane << 2];
    float4 bv = *(const float4*)&be[lane << 2];
    float4 o;
    o.x = dx * rs * gv.x + bv.x;
    o.y = dy * rs * gv.y + bv.y;
    o.z = dz * rs * gv.z + bv.z;
    o.w = dw * rs * gv.w + bv.w;
    if (mode == 1) { o.x += v.x; o.y += v.y; o.z += v.z; o.w += v.w; }
    *(float4*)&out[(size_t)row * ND + (lane << 2)] = o;
}

// ---------------------------------------------------------------------------
extern "C" void kernel_launch(void* const* d_in, const int* in_sizes, int n_in,
                              void* d_out, int out_size, void* d_ws, size_t ws_size,
                              hipStream_t stream)
{
    const float* x      = (const float*)d_in[0];
    const float* hidden = (const float*)d_in[1];
    const float* Wq = (const float*)d_in[2];
    const float* bq = (const float*)d_in[3];
    const float* Wk = (const float*)d_in[4];
    const float* bk = (const float*)d_in[5];
    const float* Wv = (const float*)d_in[6];
    const float* bv = (const float*)d_in[7];
    const float* Wo = (const float*)d_in[8];
    const float* bo = (const float*)d_in[9];
    const float* g1  = (const float*)d_in[10];
    const float* be1 = (const float*)d_in[11];
    const float* g2  = (const float*)d_in[12];
    const float* be2 = (const float*)d_in[13];
    const float* W1 = (const float*)d_in[14];
    const float* b1 = (const float*)d_in[15];
    const float* W2 = (const float*)d_in[16];
    const float* b2 = (const float*)d_in[17];

    float* out  = (float*)d_out;
    float* attn = out + (size_t)NM * ND;          // 8,388,608 floats in

    float* ws   = (float*)d_ws;
    float* qp   = ws;                              // [B,H,S,d]  (scaled q + hidden)
    float* kb   = ws + (size_t)8388608;            // [B,H,S,d]
    float* vbuf = ws + (size_t)16777216;           // [B,H,S,d]
    float* ff   = ws + (size_t)25165824;           // [M,F] 16.8M floats
    float* ctx  = kb;                              // reuse: k dead after scores
    float* hbuf = vbuf;                            // reuse: v dead after PV
    float* hn   = qp;                              // reuse: q dead after scores

    // 1. QKV projections (q gets +hidden and *1/sqrt(d))
    gemm_qkv<<<dim3(ND / 64, NM / 64, 3), 256, 0, stream>>>(
        x, Wq, Wk, Wv, bq, bk, bv, hidden, qp, kb, vbuf);
    // 2. scores + softmax -> attn (second output)
    attn_scores<<<dim3(NS / 64, NB * NH), 1024, 0, stream>>>(qp, kb, attn);
    // 3. ctx = attn @ V, re-assembled to [B,S,D]
    attn_pv<<<dim3(NS / 64, NB * NH), 256, 0, stream>>>(attn, vbuf, ctx);
    // 4. h = 2*(ctx @ Wo.T + bo)
    gemm_epi<<<dim3(ND / 64, NM / 64), 256, 0, stream>>>(ctx, Wo, bo, hbuf, ND, ND, 0);
    // 5. hn = LN1(h)
    ln_kernel<<<NM / 4, 256, 0, stream>>>(hbuf, g1, be1, hn, 0);
    // 6. ff = relu(hn @ W1.T + b1)
    gemm_epi<<<dim3(NF / 64, NM / 64), 256, 0, stream>>>(hn, W1, b1, ff, NF, ND, 1);
    // 7. h += ff @ W2.T + b2
    gemm_epi<<<dim3(ND / 64, NM / 64), 256, 0, stream>>>(ff, W2, b2, hbuf, ND, NF, 2);
    // 8. out = h + LN2(h)
    ln_kernel<<<NM / 4, 256, 0, stream>>>(hbuf, g2, be2, out, 1);
}

// Round 2
// 1110.334 us; speedup vs baseline: 1.4523x; 1.4523x over previous
//
#include <hip/hip_runtime.h>

typedef __attribute__((ext_vector_type(8))) short short8;
typedef __attribute__((ext_vector_type(4))) float f32x4;

constexpr int NB  = 32;
constexpr int NS  = 1024;
constexpr int ND  = 256;
constexpr int NH  = 8;
constexpr int NDH = 32;
constexpr int NF  = 512;
constexpr int NM  = NB * NS;          // 32768 rows
#define RSD 0.17677669529663687f       // 1/sqrt(32)

static __device__ __forceinline__ ushort f2bf(float f) {
    union { float f; unsigned u; } v; v.f = f;
    unsigned r = v.u + 0x7fffu + ((v.u >> 16) & 1u);   // round-to-nearest-even
    return (ushort)(r >> 16);
}
static __device__ __forceinline__ float bf2f(ushort u) {
    union { unsigned u; float f; } v; v.u = (unsigned)u << 16; return v.f;
}

// ---------------------------------------------------------------------------
// QKV projection. z=0: q -> (q+hidden)*RSD, split to bf16 hi/lo (qhi/qlo).
// z=1: k -> bf16 hi/lo (khi/klo). z=2: v -> fp32 [B,H,S,d].
// ---------------------------------------------------------------------------
__global__ __launch_bounds__(256) void gemm_qkv(
    const float* __restrict__ x,
    const float* __restrict__ Wq, const float* __restrict__ Wk, const float* __restrict__ Wv,
    const float* __restrict__ bq, const float* __restrict__ bk, const float* __restrict__ bv,
    const float* __restrict__ hidden,
    ushort* __restrict__ qhi, ushort* __restrict__ qlo,
    ushort* __restrict__ khi, ushort* __restrict__ klo,
    float* __restrict__ vb)
{
    __shared__ float As[16][68];
    __shared__ float Bs[16][68];
    const int t = threadIdx.x;
    const int z = blockIdx.z;
    const int rbase = blockIdx.y << 6;
    const int jbase = blockIdx.x << 6;
    const float* W    = (z == 0) ? Wq : (z == 1) ? Wk : Wv;
    const float* bias = (z == 0) ? bq : (z == 1) ? bk : bv;
    ushort* oh = (z == 0) ? qhi : khi;
    ushort* ol = (z == 0) ? qlo : klo;

    const int lr = t >> 2;
    const int lc = (t & 3) << 2;
    const int tx = t & 15, ty = t >> 4;
    float acc[4][4] = {};

    for (int k0 = 0; k0 < ND; k0 += 16) {
        float4 av = *(const float4*)&x[(size_t)(rbase + lr) * ND + k0 + lc];
        float4 wv = *(const float4*)&W[(size_t)(jbase + lr) * ND + k0 + lc];
        __syncthreads();
        As[lc + 0][lr] = av.x; As[lc + 1][lr] = av.y; As[lc + 2][lr] = av.z; As[lc + 3][lr] = av.w;
        Bs[lc + 0][lr] = wv.x; Bs[lc + 1][lr] = wv.y; Bs[lc + 2][lr] = wv.z; Bs[lc + 3][lr] = wv.w;
        __syncthreads();
        #pragma unroll
        for (int kk = 0; kk < 16; ++kk) {
            float4 a4 = *(const float4*)&As[kk][ty << 2];
            float4 b4 = *(const float4*)&Bs[kk][tx << 2];
            float a[4] = {a4.x, a4.y, a4.z, a4.w};
            float b[4] = {b4.x, b4.y, b4.z, b4.w};
            #pragma unroll
            for (int i2 = 0; i2 < 4; ++i2)
                #pragma unroll
                for (int j2 = 0; j2 < 4; ++j2)
                    acc[i2][j2] += a[i2] * b[j2];
        }
    }

    const int jcol = jbase + (tx << 2);
    const int hh = jcol >> 5, dd0 = jcol & 31;
    float4 bias4 = *(const float4*)&bias[jcol];
    #pragma unroll
    for (int i2 = 0; i2 < 4; ++i2) {
        int r = rbase + (ty << 2) + i2;
        int b_i = r >> 10, s_i = r & 1023;
        size_t idx = (((size_t)(b_i * NH + hh)) * NS + s_i) * NDH + dd0;
        float4 o;
        o.x = acc[i2][0] + bias4.x;
        o.y = acc[i2][1] + bias4.y;
        o.z = acc[i2][2] + bias4.z;
        o.w = acc[i2][3] + bias4.w;
        if (z == 0) {
            float4 hv = *(const float4*)&hidden[idx];
            o.x = (o.x + hv.x) * RSD;
            o.y = (o.y + hv.y) * RSD;
            o.z = (o.z + hv.z) * RSD;
            o.w = (o.w + hv.w) * RSD;
        }
        if (z == 2) {
            *(float4*)&vb[idx] = o;
        } else {
            ushort4 hv4, lv4;
            hv4.x = f2bf(o.x); lv4.x = f2bf(o.x - bf2f(hv4.x));
            hv4.y = f2bf(o.y); lv4.y = f2bf(o.y - bf2f(hv4.y));
            hv4.z = f2bf(o.z); lv4.z = f2bf(o.z - bf2f(hv4.z));
            hv4.w = f2bf(o.w); lv4.w = f2bf(o.w - bf2f(hv4.w));
            *(ushort4*)&oh[idx] = hv4;
            *(ushort4*)&ol[idx] = lv4;
        }
    }
}

// ---------------------------------------------------------------------------
// Generic row-major GEMM  out = epi(A @ W.T + bias)   (unchanged from R1)
// ---------------------------------------------------------------------------
__global__ __launch_bounds__(256) void gemm_epi(
    const float* __restrict__ A, const float* __restrict__ W,
    const float* __restrict__ bias, float* __restrict__ out,
    int N, int K, int epi)
{
    __shared__ float As[16][68];
    __shared__ float Bs[16][68];
    const int t = threadIdx.x;
    const int rbase = blockIdx.y << 6;
    const int jbase = blockIdx.x << 6;
    const int lr = t >> 2;
    const int lc = (t & 3) << 2;
    const int tx = t & 15, ty = t >> 4;
    float acc[4][4] = {};

    for (int k0 = 0; k0 < K; k0 += 16) {
        float4 av = *(const float4*)&A[(size_t)(rbase + lr) * K + k0 + lc];
        float4 wv = *(const float4*)&W[(size_t)(jbase + lr) * K + k0 + lc];
        __syncthreads();
        As[lc + 0][lr] = av.x; As[lc + 1][lr] = av.y; As[lc + 2][lr] = av.z; As[lc + 3][lr] = av.w;
        Bs[lc + 0][lr] = wv.x; Bs[lc + 1][lr] = wv.y; Bs[lc + 2][lr] = wv.z; Bs[lc + 3][lr] = wv.w;
        __syncthreads();
        #pragma unroll
        for (int kk = 0; kk < 16; ++kk) {
            float4 a4 = *(const float4*)&As[kk][ty << 2];
            float4 b4 = *(const float4*)&Bs[kk][tx << 2];
            float a[4] = {a4.x, a4.y, a4.z, a4.w};
            float b[4] = {b4.x, b4.y, b4.z, b4.w};
            #pragma unroll
            for (int i2 = 0; i2 < 4; ++i2)
                #pragma unroll
                for (int j2 = 0; j2 < 4; ++j2)
                    acc[i2][j2] += a[i2] * b[j2];
        }
    }

    const int jcol = jbase + (tx << 2);
    float4 bias4 = *(const float4*)&bias[jcol];
    #pragma unroll
    for (int i2 = 0; i2 < 4; ++i2) {
        int r = rbase + (ty << 2) + i2;
        float4 o;
        o.x = acc[i2][0] + bias4.x;
        o.y = acc[i2][1] + bias4.y;
        o.z = acc[i2][2] + bias4.z;
        o.w = acc[i2][3] + bias4.w;
        size_t oidx = (size_t)r * N + jcol;
        if (epi == 0) {
            o.x *= 2.f; o.y *= 2.f; o.z *= 2.f; o.w *= 2.f;
        } else if (epi == 1) {
            o.x = fmaxf(o.x, 0.f); o.y = fmaxf(o.y, 0.f);
            o.z = fmaxf(o.z, 0.f); o.w = fmaxf(o.w, 0.f);
        } else {
            float4 old = *(const float4*)&out[oidx];
            o.x += old.x; o.y += old.y; o.z += old.z; o.w += old.w;
        }
        *(float4*)&out[oidx] = o;
    }
}

// ---------------------------------------------------------------------------
// Scores + softmax via 3-term bf16-split MFMA. Block = 256 thr = 4 waves,
// 16 q-rows x full 1024 k of one (b,h). Wave w owns k-strip [256w, 256w+256).
// Per wave: 16 tiles of 16x16, one mfma_f32_16x16x32_bf16 x3 per tile.
// Fragments loaded directly from global (per-bh K = 128 KB, L1/L2 resident;
// XCD-chunk swizzle keeps each bh's 64 q-blocks on one XCD).
// ---------------------------------------------------------------------------
__global__ __launch_bounds__(256, 3) void attn_scores_mfma(
    const ushort* __restrict__ qhi, const ushort* __restrict__ qlo,
    const ushort* __restrict__ khi, const ushort* __restrict__ klo,
    float* __restrict__ attn)
{
    __shared__ float red[2][4][16];
    const int bid = blockIdx.x;
    const int lid = (bid & 7) * 2048 + (bid >> 3);   // bijective: 16384 % 8 == 0
    const int qt = lid & 63, bh = lid >> 6;
    const int q0 = qt << 4;
    const int t  = threadIdx.x;
    const int w  = t >> 6, ln = t & 63;
    const int col = ln & 15, quad = ln >> 4;

    const size_t bhbase = (size_t)bh * NS * NDH;
    const size_t aoff = bhbase + (size_t)(q0 + col) * NDH + quad * 8;
    const short8 ahi = *(const short8*)(qhi + aoff);
    const short8 alo = *(const short8*)(qlo + aoff);

    const int ks0 = w << 8;
    f32x4 acc[16];
    #pragma unroll
    for (int tl = 0; tl < 16; ++tl) {
        const size_t boff = bhbase + (size_t)(ks0 + tl * 16 + col) * NDH + quad * 8;
        short8 bhi = *(const short8*)(khi + boff);
        short8 blo = *(const short8*)(klo + boff);
        f32x4 c = {0.f, 0.f, 0.f, 0.f};
        c = __builtin_amdgcn_mfma_f32_16x16x32_bf16(ahi, bhi, c, 0, 0, 0);
        c = __builtin_amdgcn_mfma_f32_16x16x32_bf16(ahi, blo, c, 0, 0, 0);
        c = __builtin_amdgcn_mfma_f32_16x16x32_bf16(alo, bhi, c, 0, 0, 0);
        acc[tl] = c;
    }

    // ---- softmax over k (rows q0+quad*4+r owned jointly by 4 k-strip waves)
    float gm[4], sum[4], inv[4];
    #pragma unroll
    for (int r = 0; r < 4; ++r) {
        float m = acc[0][r];
        #pragma unroll
        for (int tl = 1; tl < 16; ++tl) m = fmaxf(m, acc[tl][r]);
        #pragma unroll
        for (int s = 8; s >= 1; s >>= 1) m = fmaxf(m, __shfl_xor(m, s, 64));
        gm[r] = m;
    }
    #pragma unroll
    for (int r = 0; r < 4; ++r)
        if (col == r) red[0][w][quad * 4 + r] = gm[r];
    __syncthreads();
    #pragma unroll
    for (int r = 0; r < 4; ++r) {
        const int row = quad * 4 + r;
        gm[r] = fmaxf(fmaxf(red[0][0][row], red[0][1][row]),
                      fmaxf(red[0][2][row], red[0][3][row]));
        sum[r] = 0.f;
    }
    #pragma unroll
    for (int tl = 0; tl < 16; ++tl) {
        #pragma unroll
        for (int r = 0; r < 4; ++r) {
            float e = __expf(acc[tl][r] - gm[r]);
            acc[tl][r] = e;
            sum[r] += e;
        }
    }
    #pragma unroll
    for (int r = 0; r < 4; ++r) {
        #pragma unroll
        for (int s = 8; s >= 1; s >>= 1) sum[r] += __shfl_xor(sum[r], s, 64);
        if (col == r) red[1][w][quad * 4 + r] = sum[r];
    }
    __syncthreads();
    #pragma unroll
    for (int r = 0; r < 4; ++r) {
        const int row = quad * 4 + r;
        inv[r] = 1.f / (red[1][0][row] + red[1][1][row] + red[1][2][row] + red[1][3][row]);
    }

    float* abase = attn + ((size_t)bh * NS + q0) * NS + ks0;
    #pragma unroll
    for (int tl = 0; tl < 16; ++tl) {
        #pragma unroll
        for (int r = 0; r < 4; ++r)
            abase[(size_t)(quad * 4 + r) * NS + tl * 16 + col] = acc[tl][r] * inv[r];
    }
}

// ---------------------------------------------------------------------------
// PV via 3-term bf16-split MFMA. Block = 256 thr = 4 waves, 64 q x 32 dd.
// V^T hi/lo for a 128-k chunk staged in LDS (stride 136 bf16 -> minimal
// ds_read_b128 conflicts); attn converted to bf16 hi/lo on the fly.
// ---------------------------------------------------------------------------
constexpr int VS = 136;
__global__ __launch_bounds__(256) void attn_pv_mfma(
    const float* __restrict__ attn, const float* __restrict__ vb,
    float* __restrict__ ctx)
{
    __shared__ ushort Vthi[32 * VS];
    __shared__ ushort Vtlo[32 * VS];
    const int t = threadIdx.x;
    const int w = t >> 6, ln = t & 63;
    const int col = ln & 15, quad = ln >> 4;
    const int bh = blockIdx.y;
    const int q0 = blockIdx.x << 6;
    const float* vbase = vb + (size_t)bh * NS * NDH;
    const int sdd = t & 31, skg = (t >> 5) << 4;

    f32x4 acc0 = {0.f, 0.f, 0.f, 0.f}, acc1 = {0.f, 0.f, 0.f, 0.f};

    for (int k0 = 0; k0 < NS; k0 += 128) {
        __syncthreads();
        // stage transposed V chunk: thread owns (dd=sdd, k = skg..skg+15)
        ushort hs[16], ls[16];
        #pragma unroll
        for (int c = 0; c < 16; ++c) {
            float xx = vbase[(size_t)(k0 + skg + c) * NDH + sdd];
            ushort h = f2bf(xx);
            hs[c] = h; ls[c] = f2bf(xx - bf2f(h));
        }
        #pragma unroll
        for (int c4 = 0; c4 < 4; ++c4) {
            ushort4 hv = make_ushort4(hs[c4 * 4], hs[c4 * 4 + 1], hs[c4 * 4 + 2], hs[c4 * 4 + 3]);
            ushort4 lv = make_ushort4(ls[c4 * 4], ls[c4 * 4 + 1], ls[c4 * 4 + 2], ls[c4 * 4 + 3]);
            *(ushort4*)&Vthi[sdd * VS + skg + c4 * 4] = hv;
            *(ushort4*)&Vtlo[sdd * VS + skg + c4 * 4] = lv;
        }
        __syncthreads();

        #pragma unroll
        for (int sl = 0; sl < 4; ++sl) {
            const int kl = sl * 32 + quad * 8;
            const float* ap = attn + ((size_t)bh * NS + q0 + 16 * w + col) * NS + k0 + kl;
            float4 a0 = *(const float4*)ap;
            float4 a1 = *(const float4*)(ap + 4);
            float av[8] = {a0.x, a0.y, a0.z, a0.w, a1.x, a1.y, a1.z, a1.w};
            short8 ahi, alo;
            #pragma unroll
            for (int e = 0; e < 8; ++e) {
                ushort h = f2bf(av[e]);
                ahi[e] = (short)h;
                alo[e] = (short)f2bf(av[e] - bf2f(h));
            }
            short8 bhi0 = *(const short8*)&Vthi[col * VS + kl];
            short8 blo0 = *(const short8*)&Vtlo[col * VS + kl];
            short8 bhi1 = *(const short8*)&Vthi[(16 + col) * VS + kl];
            short8 blo1 = *(const short8*)&Vtlo[(16 + col) * VS + kl];
            acc0 = __builtin_amdgcn_mfma_f32_16x16x32_bf16(ahi, bhi0, acc0, 0, 0, 0);
            acc0 = __builtin_amdgcn_mfma_f32_16x16x32_bf16(ahi, blo0, acc0, 0, 0, 0);
            acc0 = __builtin_amdgcn_mfma_f32_16x16x32_bf16(alo, bhi0, acc0, 0, 0, 0);
            acc1 = __builtin_amdgcn_mfma_f32_16x16x32_bf16(ahi, bhi1, acc1, 0, 0, 0);
            acc1 = __builtin_amdgcn_mfma_f32_16x16x32_bf16(ahi, blo1, acc1, 0, 0, 0);
            acc1 = __builtin_amdgcn_mfma_f32_16x16x32_bf16(alo, bhi1, acc1, 0, 0, 0);
        }
    }

    const int b_i = bh >> 3, hh = bh & 7;
    const int qrow = q0 + 16 * w + quad * 4;
    #pragma unroll
    for (int r = 0; r < 4; ++r) {
        size_t base = ((size_t)b_i * NS + qrow + r) * ND + hh * NDH;
        ctx[base + col]      = acc0[r];
        ctx[base + 16 + col] = acc1[r];
    }
}

// ---------------------------------------------------------------------------
// LayerNorm, one wave per row. mode 0: out = LN(x); mode 1: out = x + LN(x).
// ---------------------------------------------------------------------------
__global__ __launch_bounds__(256) void ln_kernel(
    const float* __restrict__ x, const float* __restrict__ g,
    const float* __restrict__ be, float* __restrict__ out, int mode)
{
    const int t = threadIdx.x;
    const int wave = t >> 6, lane = t & 63;
    const int row = (blockIdx.x << 2) + wave;
    const float* xr = x + (size_t)row * ND;
    float4 v = *(const float4*)&xr[lane << 2];
    float s = v.x + v.y + v.z + v.w;
    #pragma unroll
    for (int m = 32; m >= 1; m >>= 1) s += __shfl_xor(s, m, 64);
    float mu = s * (1.f / 256.f);
    float dx = v.x - mu, dy = v.y - mu, dz = v.z - mu, dw = v.w - mu;
    float s2 = dx * dx + dy * dy + dz * dz + dw * dw;
    #pragma unroll
    for (int m = 32; m >= 1; m >>= 1) s2 += __shfl_xor(s2, m, 64);
    float rs = rsqrtf(s2 * (1.f / 256.f) + 1e-5f);
    float4 gv = *(const float4*)&g[lane << 2];
    float4 bv = *(const float4*)&be[lane << 2];
    float4 o;
    o.x = dx * rs * gv.x + bv.x;
    o.y = dy * rs * gv.y + bv.y;
    o.z = dz * rs * gv.z + bv.z;
    o.w = dw * rs * gv.w + bv.w;
    if (mode == 1) { o.x += v.x; o.y += v.y; o.z += v.z; o.w += v.w; }
    *(float4*)&out[(size_t)row * ND + (lane << 2)] = o;
}

// ---------------------------------------------------------------------------
extern "C" void kernel_launch(void* const* d_in, const int* in_sizes, int n_in,
                              void* d_out, int out_size, void* d_ws, size_t ws_size,
                              hipStream_t stream)
{
    const float* x      = (const float*)d_in[0];
    const float* hidden = (const float*)d_in[1];
    const float* Wq = (const float*)d_in[2];
    const float* bq = (const float*)d_in[3];
    const float* Wk = (const float*)d_in[4];
    const float* bk = (const float*)d_in[5];
    const float* Wv = (const float*)d_in[6];
    const float* bv = (const float*)d_in[7];
    const float* Wo = (const float*)d_in[8];
    const float* bo = (const float*)d_in[9];
    const float* g1  = (const float*)d_in[10];
    const float* be1 = (const float*)d_in[11];
    const float* g2  = (const float*)d_in[12];
    const float* be2 = (const float*)d_in[13];
    const float* W1 = (const float*)d_in[14];
    const float* b1 = (const float*)d_in[15];
    const float* W2 = (const float*)d_in[16];
    const float* b2 = (const float*)d_in[17];

    float* out  = (float*)d_out;
    float* attn = out + (size_t)NM * ND;

    float* ws   = (float*)d_ws;
    ushort* qhi = (ushort*)ws;                       // [B,H,S,32] bf16 hi
    ushort* qlo = qhi + (size_t)8388608;             // lo (same region as old qp)
    ushort* khi = (ushort*)(ws + (size_t)8388608);   // old kb region
    ushort* klo = khi + (size_t)8388608;
    float* vbuf = ws + (size_t)16777216;             // [B,H,S,d] fp32
    float* ff   = ws + (size_t)25165824;             // [M,F]
    float* ctx  = ws + (size_t)8388608;              // reuse: khi/klo dead after scores
    float* hbuf = vbuf;                              // reuse: v dead after PV
    float* hn   = ws;                                // reuse: qhi/qlo dead after scores

    // 1. QKV projections (q/k emitted as bf16 hi/lo splits)
    gemm_qkv<<<dim3(ND / 64, NM / 64, 3), 256, 0, stream>>>(
        x, Wq, Wk, Wv, bq, bk, bv, hidden, qhi, qlo, khi, klo, vbuf);
    // 2. scores + softmax -> attn (MFMA 3-term split)
    attn_scores_mfma<<<dim3(16384), 256, 0, stream>>>(qhi, qlo, khi, klo, attn);
    // 3. ctx = attn @ V (MFMA 3-term split)
    attn_pv_mfma<<<dim3(NS / 64, NB * NH), 256, 0, stream>>>(attn, vbuf, ctx);
    // 4. h = 2*(ctx @ Wo.T + bo)
    gemm_epi<<<dim3(ND / 64, NM / 64), 256, 0, stream>>>(ctx, Wo, bo, hbuf, ND, ND, 0);
    // 5. hn = LN1(h)
    ln_kernel<<<NM / 4, 256, 0, stream>>>(hbuf, g1, be1, hn, 0);
    // 6. ff = relu(hn @ W1.T + b1)
    gemm_epi<<<dim3(NF / 64, NM / 64), 256, 0, stream>>>(hn, W1, b1, ff, NF, ND, 1);
    // 7. h += ff @ W2.T + b2
    gemm_epi<<<dim3(ND / 64, NM / 64), 256, 0, stream>>>(ff, W2, b2, hbuf, ND, NF, 2);
    // 8. out = h + LN2(h)
    ln_kernel<<<NM / 4, 256, 0, stream>>>(hbuf, g2, be2, out, 1);
}

// Round 3
// 906.139 us; speedup vs baseline: 1.7796x; 1.2253x over previous
//
#include <hip/hip_runtime.h>

typedef __attribute__((ext_vector_type(8))) short short8;
typedef __attribute__((ext_vector_type(4))) float f32x4;

constexpr int NB  = 32;
constexpr int NS  = 1024;
constexpr int ND  = 256;
constexpr int NH  = 8;
constexpr int NDH = 32;
constexpr int NF  = 512;
constexpr int NM  = NB * NS;          // 32768 rows
#define RSD 0.17677669529663687f       // 1/sqrt(32)

static __device__ __forceinline__ ushort f2bf(float f) {
    union { float f; unsigned u; } v; v.f = f;
    unsigned r = v.u + 0x7fffu + ((v.u >> 16) & 1u);   // round-to-nearest-even
    return (ushort)(r >> 16);
}
static __device__ __forceinline__ float bf2f(ushort u) {
    union { unsigned u; float f; } v; v.u = (unsigned)u << 16; return v.f;
}

// ---------------------------------------------------------------------------
// fp32 -> bf16 hi/lo split, float4-vectorized.
// ---------------------------------------------------------------------------
__global__ __launch_bounds__(256) void split_fp32(
    const float* __restrict__ in, ushort* __restrict__ hi, ushort* __restrict__ lo, int n4)
{
    int i = blockIdx.x * 256 + threadIdx.x;
    if (i >= n4) return;
    float4 v = ((const float4*)in)[i];
    ushort4 h, l;
    h.x = f2bf(v.x); l.x = f2bf(v.x - bf2f(h.x));
    h.y = f2bf(v.y); l.y = f2bf(v.y - bf2f(h.y));
    h.z = f2bf(v.z); l.z = f2bf(v.z - bf2f(h.z));
    h.w = f2bf(v.w); l.w = f2bf(v.w - bf2f(h.w));
    ((ushort4*)hi)[i] = h;
    ((ushort4*)lo)[i] = l;
}

// ---------------------------------------------------------------------------
// MFMA GEMM core macro pieces: 128x128 tile, BK=32, 4 waves (2x2, 64x64 each).
// LDS pad-to-40 stride: bank starts (r*20)%32 cycle over 8 positions -> 2-way.
// ---------------------------------------------------------------------------
#define GEMM_CORE(K_)                                                          \
    __shared__ ushort sAh[128 * 40], sAl[128 * 40];                            \
    __shared__ ushort sBh[128 * 40], sBl[128 * 40];                            \
    const int t = threadIdx.x;                                                 \
    const int w = t >> 6, ln = t & 63;                                         \
    const int wr = w >> 1, wc = w & 1;                                         \
    const int col = ln & 15, quad = ln >> 4;                                   \
    const int srow = t >> 1, skb = (t & 1) << 4;                               \
    const ushort* gAh = Ahi + (size_t)(rbase + srow) * (K_) + skb;             \
    const ushort* gAl = Alo + (size_t)(rbase + srow) * (K_) + skb;             \
    const ushort* gBh = Whi + (size_t)(jbase + srow) * (K_) + skb;             \
    const ushort* gBl = Wlo + (size_t)(jbase + srow) * (K_) + skb;             \
    ushort* wAh = &sAh[srow * 40 + skb];                                       \
    ushort* wAl = &sAl[srow * 40 + skb];                                       \
    ushort* wBh = &sBh[srow * 40 + skb];                                       \
    ushort* wBl = &sBl[srow * 40 + skb];                                       \
    f32x4 acc[4][4] = {};                                                      \
    for (int k0 = 0; k0 < (K_); k0 += 32) {                                    \
        short8 a0 = *(const short8*)(gAh + k0);                                \
        short8 a1 = *(const short8*)(gAh + k0 + 8);                            \
        short8 c0 = *(const short8*)(gAl + k0);                                \
        short8 c1 = *(const short8*)(gAl + k0 + 8);                            \
        short8 b0 = *(const short8*)(gBh + k0);                                \
        short8 b1 = *(const short8*)(gBh + k0 + 8);                            \
        short8 d0 = *(const short8*)(gBl + k0);                                \
        short8 d1 = *(const short8*)(gBl + k0 + 8);                            \
        __syncthreads();                                                       \
        *(short8*)wAh = a0; *(short8*)(wAh + 8) = a1;                          \
        *(short8*)wAl = c0; *(short8*)(wAl + 8) = c1;                          \
        *(short8*)wBh = b0; *(short8*)(wBh + 8) = b1;                          \
        *(short8*)wBl = d0; *(short8*)(wBl + 8) = d1;                          \
        __syncthreads();                                                       \
        short8 af[4], afl[4], bf[4], bfl[4];                                   \
        _Pragma("unroll")                                                      \
        for (int m = 0; m < 4; ++m) {                                          \
            af[m]  = *(const short8*)&sAh[(wr * 64 + m * 16 + col) * 40 + quad * 8]; \
            afl[m] = *(const short8*)&sAl[(wr * 64 + m * 16 + col) * 40 + quad * 8]; \
            bf[m]  = *(const short8*)&sBh[(wc * 64 + m * 16 + col) * 40 + quad * 8]; \
            bfl[m] = *(const short8*)&sBl[(wc * 64 + m * 16 + col) * 40 + quad * 8]; \
        }                                                                      \
        _Pragma("unroll")                                                      \
        for (int m = 0; m < 4; ++m)                                            \
            _Pragma("unroll")                                                  \
            for (int n = 0; n < 4; ++n) {                                      \
                acc[m][n] = __builtin_amdgcn_mfma_f32_16x16x32_bf16(af[m],  bf[n],  acc[m][n], 0, 0, 0); \
                acc[m][n] = __builtin_amdgcn_mfma_f32_16x16x32_bf16(af[m],  bfl[n], acc[m][n], 0, 0, 0); \
                acc[m][n] = __builtin_amdgcn_mfma_f32_16x16x32_bf16(afl[m], bf[n],  acc[m][n], 0, 0, 0); \
            }                                                                  \
    }

// ---------------------------------------------------------------------------
// Generic MFMA GEMM: out = epi(A @ W.T + bias).
// epi 0: outf = 2*(v)          (O-proj)
// epi 1: ohi/olo = split(relu) (FFN1)
// epi 2: outf += v             (FFN2 accumulate)
// ---------------------------------------------------------------------------
__global__ __launch_bounds__(256, 1) void gemm_mfma(
    const ushort* __restrict__ Ahi, const ushort* __restrict__ Alo,
    const ushort* __restrict__ Whi, const ushort* __restrict__ Wlo,
    const float* __restrict__ bias,
    float* __restrict__ outf, ushort* __restrict__ ohi, ushort* __restrict__ olo,
    int N, int K, int epi)
{
    const int rbase = blockIdx.y << 7;
    const int jbase = blockIdx.x << 7;
    GEMM_CORE(K)

    #pragma unroll
    for (int n = 0; n < 4; ++n) {
        const int cg = jbase + wc * 64 + n * 16 + col;
        const float bs = bias[cg];
        #pragma unroll
        for (int m = 0; m < 4; ++m) {
            #pragma unroll
            for (int r = 0; r < 4; ++r) {
                const int row = rbase + wr * 64 + m * 16 + quad * 4 + r;
                float v = acc[m][n][r] + bs;
                size_t oidx = (size_t)row * N + cg;
                if (epi == 0) {
                    outf[oidx] = 2.f * v;
                } else if (epi == 1) {
                    v = fmaxf(v, 0.f);
                    ushort h = f2bf(v);
                    ohi[oidx] = h;
                    olo[oidx] = f2bf(v - bf2f(h));
                } else {
                    outf[oidx] += v;
                }
            }
        }
    }
}

// ---------------------------------------------------------------------------
// QKV MFMA GEMM: z=0 -> q=(acc+b+hidden)*RSD split; z=1 -> k split; z=2 -> v fp32.
// Output scattered to [B,H,S,32].
// ---------------------------------------------------------------------------
__global__ __launch_bounds__(256, 1) void gemm_qkv_mfma(
    const ushort* __restrict__ xhi, const ushort* __restrict__ xlo,
    const ushort* __restrict__ whi, const ushort* __restrict__ wlo,
    const float* __restrict__ bq, const float* __restrict__ bk, const float* __restrict__ bv,
    const float* __restrict__ hidden,
    ushort* __restrict__ qhi, ushort* __restrict__ qlo,
    ushort* __restrict__ khi, ushort* __restrict__ klo,
    float* __restrict__ vb)
{
    const int z = blockIdx.z;
    const int rbase = blockIdx.y << 7;
    const int jbase = blockIdx.x << 7;
    const ushort* Ahi = xhi;
    const ushort* Alo = xlo;
    const ushort* Whi = whi + (size_t)z * 65536;
    const ushort* Wlo = wlo + (size_t)z * 65536;
    const float* bias = (z == 0) ? bq : (z == 1) ? bk : bv;
    GEMM_CORE(ND)

    #pragma unroll
    for (int n = 0; n < 4; ++n) {
        const int cg = jbase + wc * 64 + n * 16 + col;
        const float bs = bias[cg];
        const int hh = cg >> 5, dd = cg & 31;
        #pragma unroll
        for (int m = 0; m < 4; ++m) {
            #pragma unroll
            for (int r = 0; r < 4; ++r) {
                const int row = rbase + wr * 64 + m * 16 + quad * 4 + r;
                const int b_i = row >> 10, s_i = row & 1023;
                size_t idx = (((size_t)(b_i * NH + hh)) * NS + s_i) * NDH + dd;
                float v = acc[m][n][r] + bs;
                if (z == 2) {
                    vb[idx] = v;
                } else if (z == 0) {
                    v = (v + hidden[idx]) * RSD;
                    ushort h = f2bf(v);
                    qhi[idx] = h;
                    qlo[idx] = f2bf(v - bf2f(h));
                } else {
                    ushort h = f2bf(v);
                    khi[idx] = h;
                    klo[idx] = f2bf(v - bf2f(h));
                }
            }
        }
    }
}

// ---------------------------------------------------------------------------
// Scores + softmax via 3-term bf16-split MFMA (unchanged from R2).
// ---------------------------------------------------------------------------
__global__ __launch_bounds__(256, 3) void attn_scores_mfma(
    const ushort* __restrict__ qhi, const ushort* __restrict__ qlo,
    const ushort* __restrict__ khi, const ushort* __restrict__ klo,
    float* __restrict__ attn)
{
    __shared__ float red[2][4][16];
    const int bid = blockIdx.x;
    const int lid = (bid & 7) * 2048 + (bid >> 3);
    const int qt = lid & 63, bh = lid >> 6;
    const int q0 = qt << 4;
    const int t  = threadIdx.x;
    const int w  = t >> 6, ln = t & 63;
    const int col = ln & 15, quad = ln >> 4;

    const size_t bhbase = (size_t)bh * NS * NDH;
    const size_t aoff = bhbase + (size_t)(q0 + col) * NDH + quad * 8;
    const short8 ahi = *(const short8*)(qhi + aoff);
    const short8 alo = *(const short8*)(qlo + aoff);

    const int ks0 = w << 8;
    f32x4 acc[16];
    #pragma unroll
    for (int tl = 0; tl < 16; ++tl) {
        const size_t boff = bhbase + (size_t)(ks0 + tl * 16 + col) * NDH + quad * 8;
        short8 bhi = *(const short8*)(khi + boff);
        short8 blo = *(const short8*)(klo + boff);
        f32x4 c = {0.f, 0.f, 0.f, 0.f};
        c = __builtin_amdgcn_mfma_f32_16x16x32_bf16(ahi, bhi, c, 0, 0, 0);
        c = __builtin_amdgcn_mfma_f32_16x16x32_bf16(ahi, blo, c, 0, 0, 0);
        c = __builtin_amdgcn_mfma_f32_16x16x32_bf16(alo, bhi, c, 0, 0, 0);
        acc[tl] = c;
    }

    float gm[4], sum[4], inv[4];
    #pragma unroll
    for (int r = 0; r < 4; ++r) {
        float m = acc[0][r];
        #pragma unroll
        for (int tl = 1; tl < 16; ++tl) m = fmaxf(m, acc[tl][r]);
        #pragma unroll
        for (int s = 8; s >= 1; s >>= 1) m = fmaxf(m, __shfl_xor(m, s, 64));
        gm[r] = m;
    }
    #pragma unroll
    for (int r = 0; r < 4; ++r)
        if (col == r) red[0][w][quad * 4 + r] = gm[r];
    __syncthreads();
    #pragma unroll
    for (int r = 0; r < 4; ++r) {
        const int row = quad * 4 + r;
        gm[r] = fmaxf(fmaxf(red[0][0][row], red[0][1][row]),
                      fmaxf(red[0][2][row], red[0][3][row]));
        sum[r] = 0.f;
    }
    #pragma unroll
    for (int tl = 0; tl < 16; ++tl) {
        #pragma unroll
        for (int r = 0; r < 4; ++r) {
            float e = __expf(acc[tl][r] - gm[r]);
            acc[tl][r] = e;
            sum[r] += e;
        }
    }
    #pragma unroll
    for (int r = 0; r < 4; ++r) {
        #pragma unroll
        for (int s = 8; s >= 1; s >>= 1) sum[r] += __shfl_xor(sum[r], s, 64);
        if (col == r) red[1][w][quad * 4 + r] = sum[r];
    }
    __syncthreads();
    #pragma unroll
    for (int r = 0; r < 4; ++r) {
        const int row = quad * 4 + r;
        inv[r] = 1.f / (red[1][0][row] + red[1][1][row] + red[1][2][row] + red[1][3][row]);
    }

    float* abase = attn + ((size_t)bh * NS + q0) * NS + ks0;
    #pragma unroll
    for (int tl = 0; tl < 16; ++tl) {
        #pragma unroll
        for (int r = 0; r < 4; ++r)
            abase[(size_t)(quad * 4 + r) * NS + tl * 16 + col] = acc[tl][r] * inv[r];
    }
}

// ---------------------------------------------------------------------------
// PV via 3-term bf16-split MFMA; ctx emitted as bf16 hi/lo for the O-proj MFMA.
// ---------------------------------------------------------------------------
constexpr int VS = 136;
__global__ __launch_bounds__(256) void attn_pv_mfma(
    const float* __restrict__ attn, const float* __restrict__ vb,
    ushort* __restrict__ cthi, ushort* __restrict__ ctlo)
{
    __shared__ ushort Vthi[32 * VS];
    __shared__ ushort Vtlo[32 * VS];
    const int t = threadIdx.x;
    const int w = t >> 6, ln = t & 63;
    const int col = ln & 15, quad = ln >> 4;
    const int bh = blockIdx.y;
    const int q0 = blockIdx.x << 6;
    const float* vbase = vb + (size_t)bh * NS * NDH;
    const int sdd = t & 31, skg = (t >> 5) << 4;

    f32x4 acc0 = {0.f, 0.f, 0.f, 0.f}, acc1 = {0.f, 0.f, 0.f, 0.f};

    for (int k0 = 0; k0 < NS; k0 += 128) {
        __syncthreads();
        ushort hs[16], ls[16];
        #pragma unroll
        for (int c = 0; c < 16; ++c) {
            float xx = vbase[(size_t)(k0 + skg + c) * NDH + sdd];
            ushort h = f2bf(xx);
            hs[c] = h; ls[c] = f2bf(xx - bf2f(h));
        }
        #pragma unroll
        for (int c4 = 0; c4 < 4; ++c4) {
            ushort4 hv = make_ushort4(hs[c4 * 4], hs[c4 * 4 + 1], hs[c4 * 4 + 2], hs[c4 * 4 + 3]);
            ushort4 lv = make_ushort4(ls[c4 * 4], ls[c4 * 4 + 1], ls[c4 * 4 + 2], ls[c4 * 4 + 3]);
            *(ushort4*)&Vthi[sdd * VS + skg + c4 * 4] = hv;
            *(ushort4*)&Vtlo[sdd * VS + skg + c4 * 4] = lv;
        }
        __syncthreads();

        #pragma unroll
        for (int sl = 0; sl < 4; ++sl) {
            const int kl = sl * 32 + quad * 8;
            const float* ap = attn + ((size_t)bh * NS + q0 + 16 * w + col) * NS + k0 + kl;
            float4 a0 = *(const float4*)ap;
            float4 a1 = *(const float4*)(ap + 4);
            float av[8] = {a0.x, a0.y, a0.z, a0.w, a1.x, a1.y, a1.z, a1.w};
            short8 ahi, alo;
            #pragma unroll
            for (int e = 0; e < 8; ++e) {
                ushort h = f2bf(av[e]);
                ahi[e] = (short)h;
                alo[e] = (short)f2bf(av[e] - bf2f(h));
            }
            short8 bhi0 = *(const short8*)&Vthi[col * VS + kl];
            short8 blo0 = *(const short8*)&Vtlo[col * VS + kl];
            short8 bhi1 = *(const short8*)&Vthi[(16 + col) * VS + kl];
            short8 blo1 = *(const short8*)&Vtlo[(16 + col) * VS + kl];
            acc0 = __builtin_amdgcn_mfma_f32_16x16x32_bf16(ahi, bhi0, acc0, 0, 0, 0);
            acc0 = __builtin_amdgcn_mfma_f32_16x16x32_bf16(ahi, blo0, acc0, 0, 0, 0);
            acc0 = __builtin_amdgcn_mfma_f32_16x16x32_bf16(alo, bhi0, acc0, 0, 0, 0);
            acc1 = __builtin_amdgcn_mfma_f32_16x16x32_bf16(ahi, bhi1, acc1, 0, 0, 0);
            acc1 = __builtin_amdgcn_mfma_f32_16x16x32_bf16(ahi, blo1, acc1, 0, 0, 0);
            acc1 = __builtin_amdgcn_mfma_f32_16x16x32_bf16(alo, bhi1, acc1, 0, 0, 0);
        }
    }

    const int b_i = bh >> 3, hh = bh & 7;
    const int qrow = q0 + 16 * w + quad * 4;
    #pragma unroll
    for (int r = 0; r < 4; ++r) {
        size_t base = ((size_t)b_i * NS + qrow + r) * ND + hh * NDH;
        float v0 = acc0[r], v1 = acc1[r];
        ushort h0 = f2bf(v0), h1 = f2bf(v1);
        cthi[base + col]      = h0;
        ctlo[base + col]      = f2bf(v0 - bf2f(h0));
        cthi[base + 16 + col] = h1;
        ctlo[base + 16 + col] = f2bf(v1 - bf2f(h1));
    }
}

// ---------------------------------------------------------------------------
// LayerNorm: ln_split -> bf16 hi/lo (feeds FFN1 MFMA); ln_final -> out = x+LN(x).
// ---------------------------------------------------------------------------
__global__ __launch_bounds__(256) void ln_split(
    const float* __restrict__ x, const float* __restrict__ g,
    const float* __restrict__ be, ushort* __restrict__ ohi, ushort* __restrict__ olo)
{
    const int t = threadIdx.x;
    const int wave = t >> 6, lane = t & 63;
    const int row = (blockIdx.x << 2) + wave;
    const float* xr = x + (size_t)row * ND;
    float4 v = *(const float4*)&xr[lane << 2];
    float s = v.x + v.y + v.z + v.w;
    #pragma unroll
    for (int m = 32; m >= 1; m >>= 1) s += __shfl_xor(s, m, 64);
    float mu = s * (1.f / 256.f);
    float dx = v.x - mu, dy = v.y - mu, dz = v.z - mu, dw = v.w - mu;
    float s2 = dx * dx + dy * dy + dz * dz + dw * dw;
    #pragma unroll
    for (int m = 32; m >= 1; m >>= 1) s2 += __shfl_xor(s2, m, 64);
    float rs = rsqrtf(s2 * (1.f / 256.f) + 1e-5f);
    float4 gv = *(const float4*)&g[lane << 2];
    float4 bv = *(const float4*)&be[lane << 2];
    float o[4];
    o[0] = dx * rs * gv.x + bv.x;
    o[1] = dy * rs * gv.y + bv.y;
    o[2] = dz * rs * gv.z + bv.z;
    o[3] = dw * rs * gv.w + bv.w;
    ushort4 h, l;
    h.x = f2bf(o[0]); l.x = f2bf(o[0] - bf2f(h.x));
    h.y = f2bf(o[1]); l.y = f2bf(o[1] - bf2f(h.y));
    h.z = f2bf(o[2]); l.z = f2bf(o[2] - bf2f(h.z));
    h.w = f2bf(o[3]); l.w = f2bf(o[3] - bf2f(h.w));
    size_t oi = ((size_t)row * ND + (lane << 2)) >> 2;
    ((ushort4*)ohi)[oi] = h;
    ((ushort4*)olo)[oi] = l;
}

__global__ __launch_bounds__(256) void ln_final(
    const float* __restrict__ x, const float* __restrict__ g,
    const float* __restrict__ be, float* __restrict__ out)
{
    const int t = threadIdx.x;
    const int wave = t >> 6, lane = t & 63;
    const int row = (blockIdx.x << 2) + wave;
    const float* xr = x + (size_t)row * ND;
    float4 v = *(const float4*)&xr[lane << 2];
    float s = v.x + v.y + v.z + v.w;
    #pragma unroll
    for (int m = 32; m >= 1; m >>= 1) s += __shfl_xor(s, m, 64);
    float mu = s * (1.f / 256.f);
    float dx = v.x - mu, dy = v.y - mu, dz = v.z - mu, dw = v.w - mu;
    float s2 = dx * dx + dy * dy + dz * dz + dw * dw;
    #pragma unroll
    for (int m = 32; m >= 1; m >>= 1) s2 += __shfl_xor(s2, m, 64);
    float rs = rsqrtf(s2 * (1.f / 256.f) + 1e-5f);
    float4 gv = *(const float4*)&g[lane << 2];
    float4 bv = *(const float4*)&be[lane << 2];
    float4 o;
    o.x = dx * rs * gv.x + bv.x + v.x;
    o.y = dy * rs * gv.y + bv.y + v.y;
    o.z = dz * rs * gv.z + bv.z + v.z;
    o.w = dw * rs * gv.w + bv.w + v.w;
    *(float4*)&out[(size_t)row * ND + (lane << 2)] = o;
}

// ---------------------------------------------------------------------------
extern "C" void kernel_launch(void* const* d_in, const int* in_sizes, int n_in,
                              void* d_out, int out_size, void* d_ws, size_t ws_size,
                              hipStream_t stream)
{
    const float* x      = (const float*)d_in[0];
    const float* hidden = (const float*)d_in[1];
    const float* Wq = (const float*)d_in[2];
    const float* bq = (const float*)d_in[3];
    const float* Wk = (const float*)d_in[4];
    const float* bk = (const float*)d_in[5];
    const float* Wv = (const float*)d_in[6];
    const float* bv = (const float*)d_in[7];
    const float* Wo = (const float*)d_in[8];
    const float* bo = (const float*)d_in[9];
    const float* g1  = (const float*)d_in[10];
    const float* be1 = (const float*)d_in[11];
    const float* g2  = (const float*)d_in[12];
    const float* be2 = (const float*)d_in[13];
    const float* W1 = (const float*)d_in[14];
    const float* b1 = (const float*)d_in[15];
    const float* W2 = (const float*)d_in[16];
    const float* b2 = (const float*)d_in[17];

    float* out  = (float*)d_out;
    float* attn = out + (size_t)NM * ND;

    float* ws = (float*)d_ws;
    // region map (float units); peak 42,467,328 floats = 169.9 MB
    ushort* xhi  = (ushort*)ws;                                   // [0, 4.19M)
    ushort* xlo  = (ushort*)(ws + 4194304);
    ushort* qhi  = (ushort*)(ws + 8388608);
    ushort* qlo  = (ushort*)(ws + 12582912);
    ushort* khi  = (ushort*)(ws + 16777216);
    ushort* klo  = (ushort*)(ws + 20971520);
    float*  vbuf = ws + 25165824;                                 // fp32 [B,H,S,32]
    ushort* cthi = (ushort*)ws;                                   // reuse x region
    ushort* ctlo = (ushort*)(ws + 4194304);
    float*  hbuf = ws + 33554432;                                 // fp32 [M,256]
    ushort* hnhi = (ushort*)(ws + 8388608);                       // reuse q region
    ushort* hnlo = (ushort*)(ws + 12582912);
    ushort* ffhi = (ushort*)(ws + 16777216);                      // reuse k region
    ushort* fflo = (ushort*)(ws + 25165824);                      // reuse v region
    ushort* whi  = (ushort*)(ws + 41943040);                      // 524288 ushorts
    ushort* wlo  = (ushort*)(ws + 42205184);

    // weight split offsets (ushort units): Wq 0, Wk 64K, Wv 128K, Wo 192K, W1 256K, W2 384K
    split_fp32<<<64, 256, 0, stream>>>(Wq, whi, wlo, 16384);
    split_fp32<<<64, 256, 0, stream>>>(Wk, whi + 65536, wlo + 65536, 16384);
    split_fp32<<<64, 256, 0, stream>>>(Wv, whi + 131072, wlo + 131072, 16384);
    split_fp32<<<64, 256, 0, stream>>>(Wo, whi + 196608, wlo + 196608, 16384);
    split_fp32<<<128, 256, 0, stream>>>(W1, whi + 262144, wlo + 262144, 32768);
    split_fp32<<<128, 256, 0, stream>>>(W2, whi + 393216, wlo + 393216, 32768);
    split_fp32<<<8192, 256, 0, stream>>>(x, xhi, xlo, 2097152);

    // 1. QKV projections (MFMA)
    gemm_qkv_mfma<<<dim3(2, 256, 3), 256, 0, stream>>>(
        xhi, xlo, whi, wlo, bq, bk, bv, hidden, qhi, qlo, khi, klo, vbuf);
    // 2. scores + softmax -> attn
    attn_scores_mfma<<<dim3(16384), 256, 0, stream>>>(qhi, qlo, khi, klo, attn);
    // 3. ctx = attn @ V -> bf16 hi/lo
    attn_pv_mfma<<<dim3(NS / 64, NB * NH), 256, 0, stream>>>(attn, vbuf, cthi, ctlo);
    // 4. h = 2*(ctx @ Wo.T + bo)
    gemm_mfma<<<dim3(2, 256), 256, 0, stream>>>(
        cthi, ctlo, whi + 196608, wlo + 196608, bo, hbuf, nullptr, nullptr, ND, ND, 0);
    // 5. hn = LN1(h) -> bf16 hi/lo
    ln_split<<<NM / 4, 256, 0, stream>>>(hbuf, g1, be1, hnhi, hnlo);
    // 6. ff = relu(hn @ W1.T + b1) -> bf16 hi/lo
    gemm_mfma<<<dim3(4, 256), 256, 0, stream>>>(
        hnhi, hnlo, whi + 262144, wlo + 262144, b1, nullptr, ffhi, fflo, NF, ND, 1);
    // 7. h += ff @ W2.T + b2
    gemm_mfma<<<dim3(2, 256), 256, 0, stream>>>(
        ffhi, fflo, whi + 393216, wlo + 393216, b2, hbuf, nullptr, nullptr, ND, NF, 2);
    // 8. out = h + LN2(h)
    ln_final<<<NM / 4, 256, 0, stream>>>(hbuf, g2, be2, out);
}